// Round 2
// baseline (1197.454 us; speedup 1.0000x reference)
//
#include <hip/hip_runtime.h>
#include <math.h>

#define B_ 2048
#define T_ 256
#define F_ 128
#define H_ 64
#define G_ 192      // 3*H
#define R_ 8        // batch rows per block
#define TC_ 8       // time steps per in-kernel chunk
#define NCH_ (T_ / TC_)   // 32 chunks
#define M_ (R_ * TC_)     // 64 gemm rows per chunk (row-major m = tt*R_ + row)

__device__ __forceinline__ float sigmoid_f(float v) {
    return 1.0f / (1.0f + __expf(-v));
}
__device__ __forceinline__ float tanh_f(float v) {
    // tanh(x) = 1 - 2/(1+e^{2x}); exp overflow -> inf -> 2/inf -> 0 -> 1 (correct)
    return 1.0f - 2.0f / (1.0f + __expf(2.0f * v));
}

// One block = 256 threads = 4 waves, owns R_=8 batch rows for the full scan.
// LDS: wT (persistent W_ih^T, 98.3KB) + gxl (chunk gates, 49.2KB)
//      + xT (per-kc x slice, 8.7KB) + h_lds (2KB) = 158.2KB <= 160KiB/CU.
__global__ __launch_bounds__(256, 1) void gru_fused_kernel(
    const float* __restrict__ x, const float* __restrict__ w_ih,
    const float* __restrict__ w_hh, const float* __restrict__ b_ih,
    const float* __restrict__ b_hh, const float* __restrict__ fc_w,
    const float* __restrict__ fc_b, float* __restrict__ out)
{
    __shared__ float wT[F_][G_];           // wT[f][g] = w_ih[g][f]
    __shared__ float gxl[TC_][R_][G_];     // gate pre-activations for the chunk
    __shared__ float xT[32][M_ + 4];       // xT[kk][m], padded
    __shared__ float h_lds[4][2][H_];      // per-wave h broadcast buffers

    const int tid = threadIdx.x;
    const int wv  = tid >> 6;              // wave id 0..3
    const int j   = tid & 63;              // lane 0..63
    const int b0  = blockIdx.x * R_;

    // ---- stage W_ih^T into LDS (once) ----
    for (int fl = tid; fl < G_ * (F_ / 4); fl += 256) {
        const int gg = fl >> 5;            // 0..191
        const int k4 = fl & 31;            // 0..31 float4 along f
        const float4 v = *(const float4*)&w_ih[gg * F_ + k4 * 4];
        wT[k4 * 4 + 0][gg] = v.x;
        wT[k4 * 4 + 1][gg] = v.y;
        wT[k4 * 4 + 2][gg] = v.z;
        wT[k4 * 4 + 3][gg] = v.w;
    }

    // ---- per-lane register copies of W_hh rows j, 64+j, 128+j ----
    float4 wr[16], wz[16], wn[16];
    #pragma unroll
    for (int k4 = 0; k4 < 16; ++k4) {
        wr[k4] = *(const float4*)&w_hh[(j)        * H_ + k4 * 4];
        wz[k4] = *(const float4*)&w_hh[(64 + j)   * H_ + k4 * 4];
        wn[k4] = *(const float4*)&w_hh[(128 + j)  * H_ + k4 * 4];
    }
    const float bR = b_hh[j], bZ = b_hh[64 + j], bN = b_hh[128 + j];
    const float bI0 = b_ih[j], bI1 = b_ih[64 + j], bI2 = b_ih[128 + j];

    // ---- h state: this wave owns rows 2*wv and 2*wv+1 ----
    float h0 = 0.0f, h1 = 0.0f;
    h_lds[wv][0][j] = 0.0f;
    h_lds[wv][1][j] = 0.0f;

    for (int c = 0; c < NCH_; ++c) {
        const int t0 = c * TC_;

        // ================= Phase A: gx for this chunk =================
        float acc[3][16];
        #pragma unroll
        for (int i = 0; i < 16; ++i) {
            acc[0][i] = bI0; acc[1][i] = bI1; acc[2][i] = bI2;
        }

        for (int kc = 0; kc < 4; ++kc) {
            __syncthreads();   // protect xT (and gxl/wT on first pass) from prior readers
            {
                const int k4 = tid & 7;    // float4 within the 32-wide k slice
                const int mq = tid >> 3;   // 0..31
                #pragma unroll
                for (int i = 0; i < 2; ++i) {
                    const int m = mq + 32 * i;            // m = tt*R_ + row
                    const int row = m & 7, tt = m >> 3;
                    const float4 v = *(const float4*)&x[
                        ((size_t)(b0 + row) * T_ + (t0 + tt)) * F_ + kc * 32 + k4 * 4];
                    xT[k4 * 4 + 0][m] = v.x;
                    xT[k4 * 4 + 1][m] = v.y;
                    xT[k4 * 4 + 2][m] = v.z;
                    xT[k4 * 4 + 3][m] = v.w;
                }
            }
            __syncthreads();

            #pragma unroll
            for (int kk = 0; kk < 32; ++kk) {
                const float w0 = wT[kc * 32 + kk][j];        // lane-indexed, conflict-free
                const float w1 = wT[kc * 32 + kk][j + 64];
                const float w2 = wT[kc * 32 + kk][j + 128];
                #pragma unroll
                for (int bi = 0; bi < 4; ++bi) {
                    const float4 xv = *(const float4*)&xT[kk][wv * 16 + bi * 4]; // broadcast
                    acc[0][bi*4+0] = fmaf(w0, xv.x, acc[0][bi*4+0]);
                    acc[0][bi*4+1] = fmaf(w0, xv.y, acc[0][bi*4+1]);
                    acc[0][bi*4+2] = fmaf(w0, xv.z, acc[0][bi*4+2]);
                    acc[0][bi*4+3] = fmaf(w0, xv.w, acc[0][bi*4+3]);
                    acc[1][bi*4+0] = fmaf(w1, xv.x, acc[1][bi*4+0]);
                    acc[1][bi*4+1] = fmaf(w1, xv.y, acc[1][bi*4+1]);
                    acc[1][bi*4+2] = fmaf(w1, xv.z, acc[1][bi*4+2]);
                    acc[1][bi*4+3] = fmaf(w1, xv.w, acc[1][bi*4+3]);
                    acc[2][bi*4+0] = fmaf(w2, xv.x, acc[2][bi*4+0]);
                    acc[2][bi*4+1] = fmaf(w2, xv.y, acc[2][bi*4+1]);
                    acc[2][bi*4+2] = fmaf(w2, xv.z, acc[2][bi*4+2]);
                    acc[2][bi*4+3] = fmaf(w2, xv.w, acc[2][bi*4+3]);
                }
            }
        }

        // write gate pre-activations to LDS
        #pragma unroll
        for (int gate = 0; gate < 3; ++gate) {
            #pragma unroll
            for (int i = 0; i < 16; ++i) {
                const int m = wv * 16 + i;
                gxl[m >> 3][m & 7][j + 64 * gate] = acc[gate][i];
            }
        }
        __syncthreads();

        // ================= Phase B: TC_ recurrence steps =================
        for (int tt = 0; tt < TC_; ++tt) {
            const int ra = wv * 2, rb = wv * 2 + 1;
            const float rx0 = gxl[tt][ra][j];
            const float zx0 = gxl[tt][ra][64 + j];
            const float nx0 = gxl[tt][ra][128 + j];
            const float rx1 = gxl[tt][rb][j];
            const float zx1 = gxl[tt][rb][64 + j];
            const float nx1 = gxl[tt][rb][128 + j];

            float aR0 = bR, aZ0 = bZ, aN0 = bN;
            float aR1 = bR, aZ1 = bZ, aN1 = bN;

            #pragma unroll
            for (int k4 = 0; k4 < 16; ++k4) {
                const float4 ha = *(const float4*)&h_lds[wv][0][k4 * 4]; // broadcast
                const float4 hb = *(const float4*)&h_lds[wv][1][k4 * 4];
                aR0 = fmaf(wr[k4].x, ha.x, aR0); aR0 = fmaf(wr[k4].y, ha.y, aR0);
                aR0 = fmaf(wr[k4].z, ha.z, aR0); aR0 = fmaf(wr[k4].w, ha.w, aR0);
                aZ0 = fmaf(wz[k4].x, ha.x, aZ0); aZ0 = fmaf(wz[k4].y, ha.y, aZ0);
                aZ0 = fmaf(wz[k4].z, ha.z, aZ0); aZ0 = fmaf(wz[k4].w, ha.w, aZ0);
                aN0 = fmaf(wn[k4].x, ha.x, aN0); aN0 = fmaf(wn[k4].y, ha.y, aN0);
                aN0 = fmaf(wn[k4].z, ha.z, aN0); aN0 = fmaf(wn[k4].w, ha.w, aN0);
                aR1 = fmaf(wr[k4].x, hb.x, aR1); aR1 = fmaf(wr[k4].y, hb.y, aR1);
                aR1 = fmaf(wr[k4].z, hb.z, aR1); aR1 = fmaf(wr[k4].w, hb.w, aR1);
                aZ1 = fmaf(wz[k4].x, hb.x, aZ1); aZ1 = fmaf(wz[k4].y, hb.y, aZ1);
                aZ1 = fmaf(wz[k4].z, hb.z, aZ1); aZ1 = fmaf(wz[k4].w, hb.w, aZ1);
                aN1 = fmaf(wn[k4].x, hb.x, aN1); aN1 = fmaf(wn[k4].y, hb.y, aN1);
                aN1 = fmaf(wn[k4].w, hb.w, aN1); aN1 = fmaf(wn[k4].z, hb.z, aN1);
            }

            const float r0 = sigmoid_f(rx0 + aR0);
            const float z0 = sigmoid_f(zx0 + aZ0);
            const float n0 = tanh_f(nx0 + r0 * aN0);
            h0 = (1.0f - z0) * n0 + z0 * h0;

            const float r1 = sigmoid_f(rx1 + aR1);
            const float z1 = sigmoid_f(zx1 + aZ1);
            const float n1 = tanh_f(nx1 + r1 * aN1);
            h1 = (1.0f - z1) * n1 + z1 * h1;

            h_lds[wv][0][j] = h0;
            h_lds[wv][1][j] = h1;
            __syncthreads();   // cheap safety: orders h_lds writes vs next-step reads
        }
    }

    // ================= Epilogue: out = h @ fc_w^T + fc_b =================
    float v0 = h0 * fc_w[j];
    float v1 = h1 * fc_w[j];
    #pragma unroll
    for (int m = 32; m >= 1; m >>= 1) {
        v0 += __shfl_xor(v0, m, 64);
        v1 += __shfl_xor(v1, m, 64);
    }
    if (j == 0) {
        out[b0 + wv * 2]     = v0 + fc_b[0];
        out[b0 + wv * 2 + 1] = v1 + fc_b[0];
    }
}

extern "C" void kernel_launch(void* const* d_in, const int* in_sizes, int n_in,
                              void* d_out, int out_size, void* d_ws, size_t ws_size,
                              hipStream_t stream)
{
    (void)in_sizes; (void)n_in; (void)out_size; (void)d_ws; (void)ws_size;
    const float* x    = (const float*)d_in[0];
    const float* w_ih = (const float*)d_in[1];
    const float* w_hh = (const float*)d_in[2];
    const float* b_ih = (const float*)d_in[3];
    const float* b_hh = (const float*)d_in[4];
    const float* fc_w = (const float*)d_in[5];
    const float* fc_b = (const float*)d_in[6];
    float* out = (float*)d_out;

    gru_fused_kernel<<<dim3(B_ / R_), 256, 0, stream>>>(
        x, w_ih, w_hh, b_ih, b_hh, fc_w, fc_b, out);
}

// Round 3
// 680.427 us; speedup vs baseline: 1.7599x; 1.7599x over previous
//
#include <hip/hip_runtime.h>
#include <math.h>

#define B_ 2048
#define T_ 256
#define F_ 128
#define H_ 64
#define G_ 192            // 3*H
#define TC_ 16            // timesteps per chunk = MFMA M-tile
#define NCH_ (T_ / TC_)   // 16 chunks
#define NW_ 8             // waves per block; wave owns 1 batch row
#define GXS 193           // gxl row stride (pad: <=2-way bank aliasing)

typedef __attribute__((ext_vector_type(8))) short short8;   // 8 bf16
typedef __attribute__((ext_vector_type(4))) float f32x4;

__device__ __forceinline__ unsigned short bf16_rne(float f) {
    unsigned int u = __float_as_uint(f);
    u += 0x7fffu + ((u >> 16) & 1u);
    return (unsigned short)(u >> 16);
}
__device__ __forceinline__ float bf16_to_f32(unsigned short h) {
    return __uint_as_float(((unsigned int)h) << 16);
}
__device__ __forceinline__ float sigmoid_f(float v) { return 1.0f / (1.0f + __expf(-v)); }
__device__ __forceinline__ float tanh_f(float v) {
    return 1.0f - 2.0f / (1.0f + __expf(2.0f * v));   // overflow -> 1, correct
}

// 512 threads = 8 waves; wave wv owns batch row blockIdx.x*8+wv for all T.
// Main loop has NO __syncthreads: all LDS traffic is wave-private (gxl, h)
// or read-only-shared (wfrag, bias).
__global__ __launch_bounds__(512, 2) void gru_fused(
    const float* __restrict__ x, const float* __restrict__ w_ih,
    const float* __restrict__ w_hh, const float* __restrict__ b_ih,
    const float* __restrict__ b_hh, const float* __restrict__ fc_w,
    const float* __restrict__ fc_b, float* __restrict__ out)
{
    __shared__ short sh_wfrag[12 * 4 * 64 * 8];       // w_ih bf16 B-frags, 48 KB
    __shared__ float sh_gxl[NW_ * TC_ * GXS];         // per-wave gx, 96.5 KB
    __shared__ float sh_bias[G_];                     // b_ih
    __shared__ float sh_h[NW_][H_];                   // per-wave h

    const int tid = threadIdx.x;
    const int wv  = tid >> 6;
    const int j   = tid & 63;
    const int brow = blockIdx.x * NW_ + wv;

    // ---- one-time staging: w_ih -> bf16 B-fragment layout ----
    // slot s=(n*4+kstep)*64+L holds 8 bf16: B[k=kstep*32+(L>>4)*8+jj][col=L&15]
    // of tile n, i.e. w_ih[n*16+(L&15)][k..k+7].
    for (int s = tid; s < 12 * 4 * 64; s += 512) {
        const int n = s >> 8;
        const int r = s & 255;
        const int ks = r >> 6;
        const int L = r & 63;
        const int g = n * 16 + (L & 15);
        const int k0 = ks * 32 + (L >> 4) * 8;
        const float4 w0 = *(const float4*)&w_ih[g * F_ + k0];
        const float4 w1 = *(const float4*)&w_ih[g * F_ + k0 + 4];
        union { short8 v; unsigned short u[8]; } fr;
        fr.u[0] = bf16_rne(w0.x); fr.u[1] = bf16_rne(w0.y);
        fr.u[2] = bf16_rne(w0.z); fr.u[3] = bf16_rne(w0.w);
        fr.u[4] = bf16_rne(w1.x); fr.u[5] = bf16_rne(w1.y);
        fr.u[6] = bf16_rne(w1.z); fr.u[7] = bf16_rne(w1.w);
        *(short8*)&sh_wfrag[s * 8] = fr.v;
    }
    for (int i = tid; i < G_; i += 512) sh_bias[i] = b_ih[i];

    // ---- per-lane W_hh rows (j, 64+j, 128+j) in registers: 192 VGPR ----
    float4 wr[16], wz[16], wn[16];
    #pragma unroll
    for (int k4 = 0; k4 < 16; ++k4) {
        wr[k4] = *(const float4*)&w_hh[(j)       * H_ + k4 * 4];
        wz[k4] = *(const float4*)&w_hh[(64 + j)  * H_ + k4 * 4];
        wn[k4] = *(const float4*)&w_hh[(128 + j) * H_ + k4 * 4];
    }
    const float bR = b_hh[j], bZ = b_hh[64 + j], bN = b_hh[128 + j];

    float* gxw = &sh_gxl[wv * TC_ * GXS];
    float* hw  = sh_h[wv];
    float hval = 0.0f;
    hw[j] = 0.0f;

    __syncthreads();   // wfrag/bias visible to all waves; ONLY barrier

    for (int c = 0; c < NCH_; ++c) {
        const int t0 = c * TC_;

        // ===== Phase A: gx[tt][g] for this wave's row via MFMA =====
        // A-frag: lane j supplies x[t0 + (j&15)][kstep*32 + (j>>4)*8 .. +7]
        const float* xb = x + ((size_t)brow * T_ + t0 + (j & 15)) * F_ + ((j >> 4) * 8);
        short8 ah[4], al[4];
        #pragma unroll
        for (int ks = 0; ks < 4; ++ks) {
            const float4 a0 = *(const float4*)(xb + ks * 32);
            const float4 a1 = *(const float4*)(xb + ks * 32 + 4);
            const float f[8] = {a0.x, a0.y, a0.z, a0.w, a1.x, a1.y, a1.z, a1.w};
            union { short8 v; unsigned short u[8]; } Hi, Lo;
            #pragma unroll
            for (int e = 0; e < 8; ++e) {
                const unsigned short hb = bf16_rne(f[e]);
                Hi.u[e] = hb;
                Lo.u[e] = bf16_rne(f[e] - bf16_to_f32(hb));
            }
            ah[ks] = Hi.v; al[ks] = Lo.v;
        }

        #pragma unroll
        for (int n = 0; n < 12; ++n) {
            const float bv = sh_bias[n * 16 + (j & 15)];
            f32x4 acc = {bv, bv, bv, bv};
            #pragma unroll
            for (int ks = 0; ks < 4; ++ks) {
                const short8 wf = *(const short8*)&sh_wfrag[((n * 4 + ks) * 64 + j) * 8];
                acc = __builtin_amdgcn_mfma_f32_16x16x32_bf16(ah[ks], wf, acc, 0, 0, 0);
                acc = __builtin_amdgcn_mfma_f32_16x16x32_bf16(al[ks], wf, acc, 0, 0, 0);
            }
            // C-layout: row(slot=tt) = (j>>4)*4+reg, col(g) = n*16+(j&15)
            const int colb = n * 16 + (j & 15);
            const int s0 = (j >> 4) * 4;
            gxw[(s0 + 0) * GXS + colb] = acc[0];
            gxw[(s0 + 1) * GXS + colb] = acc[1];
            gxw[(s0 + 2) * GXS + colb] = acc[2];
            gxw[(s0 + 3) * GXS + colb] = acc[3];
        }

        // ===== Phase B: 16 recurrence steps (wave-private, fp32) =====
        for (int tt = 0; tt < TC_; ++tt) {
            const float rx = gxw[tt * GXS + j];
            const float zx = gxw[tt * GXS + 64 + j];
            const float nx = gxw[tt * GXS + 128 + j];

            float aR = bR, aZ = bZ, aN = bN;
            #pragma unroll
            for (int k4 = 0; k4 < 16; ++k4) {
                const float4 h4 = *(const float4*)&hw[k4 * 4];   // broadcast
                aR = fmaf(wr[k4].x, h4.x, aR); aR = fmaf(wr[k4].y, h4.y, aR);
                aR = fmaf(wr[k4].z, h4.z, aR); aR = fmaf(wr[k4].w, h4.w, aR);
                aZ = fmaf(wz[k4].x, h4.x, aZ); aZ = fmaf(wz[k4].y, h4.y, aZ);
                aZ = fmaf(wz[k4].z, h4.z, aZ); aZ = fmaf(wz[k4].w, h4.w, aZ);
                aN = fmaf(wn[k4].x, h4.x, aN); aN = fmaf(wn[k4].y, h4.y, aN);
                aN = fmaf(wn[k4].z, h4.z, aN); aN = fmaf(wn[k4].w, h4.w, aN);
            }
            const float r = sigmoid_f(rx + aR);
            const float z = sigmoid_f(zx + aZ);
            const float n = tanh_f(nx + r * aN);
            hval = (1.0f - z) * n + z * hval;
            hw[j] = hval;
            __builtin_amdgcn_wave_barrier();   // pin ds ordering (free)
        }
    }

    // ===== Epilogue: out[brow] = h . fc_w + fc_b =====
    float v = hval * fc_w[j];
    #pragma unroll
    for (int m = 32; m >= 1; m >>= 1) v += __shfl_xor(v, m, 64);
    if (j == 0) out[brow] = v + fc_b[0];
}

extern "C" void kernel_launch(void* const* d_in, const int* in_sizes, int n_in,
                              void* d_out, int out_size, void* d_ws, size_t ws_size,
                              hipStream_t stream)
{
    (void)in_sizes; (void)n_in; (void)out_size; (void)d_ws; (void)ws_size;
    const float* x    = (const float*)d_in[0];
    const float* w_ih = (const float*)d_in[1];
    const float* w_hh = (const float*)d_in[2];
    const float* b_ih = (const float*)d_in[3];
    const float* b_hh = (const float*)d_in[4];
    const float* fc_w = (const float*)d_in[5];
    const float* fc_b = (const float*)d_in[6];
    float* out = (float*)d_out;

    gru_fused<<<dim3(B_ / NW_), 512, 0, stream>>>(
        x, w_ih, w_hh, b_ih, b_hh, fc_w, fc_b, out);
}

// Round 4
// 631.177 us; speedup vs baseline: 1.8972x; 1.0780x over previous
//
#include <hip/hip_runtime.h>

#define B_ 2048
#define T_ 256
#define F_ 128
#define H_ 64

typedef __attribute__((ext_vector_type(8))) short short8;   // 8 bf16
typedef __attribute__((ext_vector_type(4))) float f32x4;

// pack two floats to adjacent bf16 (RNE): low16 = a, high16 = b
__device__ __forceinline__ unsigned int rne2(float fa, float fb) {
    unsigned int ua = __float_as_uint(fa);
    unsigned int ub = __float_as_uint(fb);
    ua = ua + 0x7fffu + ((ua >> 16) & 1u);
    ub = ub + 0x7fffu + ((ub >> 16) & 1u);
    return (ua >> 16) | (ub & 0xffff0000u);
}
__device__ __forceinline__ float sigmoid_f(float v) {
    return __fdividef(1.0f, 1.0f + __expf(-v));
}
__device__ __forceinline__ float tanh_f(float v) {
    return 1.0f - __fdividef(2.0f, 1.0f + __expf(2.0f * v));  // overflow -> +/-1 correct
}

// 128 threads = 2 waves. Block owns 4 batch rows for all T=256 steps.
// Wave wv owns hidden dims [32*wv, 32*wv+32)  (G-tiles g*4 + 2*wv + n2).
// gx M-tile packs 2 timesteps x 4 rows x 2 replication: m = (sl<<3)|(rep<<2)|row.
// C-layout (verified r3): row_slot = (j>>4)*4+reg, col = tile*16 + (j&15).
// h kept in LDS as pre-split bf16 hi/lo (double-buffered), 1 barrier/step.
__global__ __launch_bounds__(128, 2) void gru_fused(
    const float* __restrict__ x, const float* __restrict__ w_ih,
    const float* __restrict__ w_hh, const float* __restrict__ b_ih,
    const float* __restrict__ b_hh, const float* __restrict__ fc_w,
    const float* __restrict__ fc_b, float* __restrict__ out)
{
    __shared__ __align__(16) short wihf[12 * 4 * 64 * 8];   // 48 KB B-frags (bf16)
    __shared__ __align__(16) short whhf[12 * 2 * 64 * 8];   // 24 KB B-frags (bf16)
    __shared__ __align__(16) short hhi_l[2][4][72];         // h hi bf16, dbuf, pad 72
    __shared__ __align__(16) short hlo_l[2][4][72];         // h lo bf16
    __shared__ float wred[2][4];

    const int tid = threadIdx.x;
    const int wv  = tid >> 6;          // 0..1
    const int j   = tid & 63;
    const int q   = j >> 4;            // 0..3
    const int c   = j & 15;            // 0..15
    const int brow = blockIdx.x * 4;

    // ---- stage w_ih B-frags: slot s=(tile*4+ks)*64+L  el e = w_ih[tile*16+(L&15)][ks*32+(L>>4)*8+e]
    for (int s = tid; s < 12 * 4 * 64; s += 128) {
        const int n = s >> 8, ks = (s >> 6) & 3, L = s & 63;
        const float* wp = w_ih + (n * 16 + (L & 15)) * F_ + ks * 32 + ((L >> 4) * 8);
        const float4 a = *(const float4*)wp;
        const float4 b = *(const float4*)(wp + 4);
        union { short8 v; unsigned int u[4]; } fr;
        fr.u[0] = rne2(a.x, a.y); fr.u[1] = rne2(a.z, a.w);
        fr.u[2] = rne2(b.x, b.y); fr.u[3] = rne2(b.z, b.w);
        *(short8*)&wihf[s * 8] = fr.v;
    }
    // ---- stage w_hh B-frags: slot s=(tile*2+ks2)*64+L  el e = w_hh[tile*16+(L&15)][ks2*32+(L>>4)*8+e]
    for (int s = tid; s < 12 * 2 * 64; s += 128) {
        const int n = s >> 7, ks2 = (s >> 6) & 1, L = s & 63;
        const float* wp = w_hh + (n * 16 + (L & 15)) * H_ + ks2 * 32 + ((L >> 4) * 8);
        const float4 a = *(const float4*)wp;
        const float4 b = *(const float4*)(wp + 4);
        union { short8 v; unsigned int u[4]; } fr;
        fr.u[0] = rne2(a.x, a.y); fr.u[1] = rne2(a.z, a.w);
        fr.u[2] = rne2(b.x, b.y); fr.u[3] = rne2(b.z, b.w);
        *(short8*)&whhf[s * 8] = fr.v;
    }
    // ---- zero h buffers
    for (int i = tid; i < 2 * 4 * 72; i += 128) {
        ((short*)hhi_l)[i] = 0;
        ((short*)hlo_l)[i] = 0;
    }

    // ---- per-lane constants
    const int d0 = wv * 32 + c;                 // hidden dim for n2=0 (n2=1 -> +16)
    float bxr[2], bxz[2], bxn[2], bgr[2], bgz[2], bgn[2];
    #pragma unroll
    for (int n2 = 0; n2 < 2; ++n2) {
        const int d = d0 + n2 * 16;
        bxr[n2] = b_ih[d];        bgr[n2] = b_hh[d];
        bxz[n2] = b_ih[64 + d];   bgz[n2] = b_hh[64 + d];
        bxn[n2] = b_ih[128 + d];  bgn[n2] = b_hh[128 + d];
    }
    const float fw0 = fc_w[d0], fw1 = fc_w[d0 + 16];

    // A-side x mapping: m = j&15 -> sl = m>>3 (step in pack), row = m&3 (rep bit m&4)
    const int xrow = (j & 15) & 3;
    const int xsl  = (j & 15) >> 3;
    const float* xlane = x + ((size_t)(brow + xrow) * T_ + xsl) * F_ + q * 8;

    __syncthreads();   // frags + zeroed h visible

    // ---- x register prefetch: 2 macro-steps deep
    float4 XA[8], XB[8];
    {
        const float* lp = xlane;
        #pragma unroll
        for (int ks = 0; ks < 4; ++ks) {
            XA[2 * ks]     = *(const float4*)(lp + ks * 32);
            XA[2 * ks + 1] = *(const float4*)(lp + ks * 32 + 4);
        }
        lp = xlane + 2 * F_;
        #pragma unroll
        for (int ks = 0; ks < 4; ++ks) {
            XB[2 * ks]     = *(const float4*)(lp + ks * 32);
            XB[2 * ks + 1] = *(const float4*)(lp + ks * 32 + 4);
        }
    }

    short8 af[4], hh[2], hl[2];
    const short8 z8 = {0, 0, 0, 0, 0, 0, 0, 0};
    hh[0] = z8; hh[1] = z8; hl[0] = z8; hl[1] = z8;

    auto cvtbuf = [&](float4 (&Xv)[8]) {
        #pragma unroll
        for (int ks = 0; ks < 4; ++ks) {
            union { short8 v; unsigned int u[4]; } fr;
            fr.u[0] = rne2(Xv[2 * ks].x,     Xv[2 * ks].y);
            fr.u[1] = rne2(Xv[2 * ks].z,     Xv[2 * ks].w);
            fr.u[2] = rne2(Xv[2 * ks + 1].x, Xv[2 * ks + 1].y);
            fr.u[3] = rne2(Xv[2 * ks + 1].z, Xv[2 * ks + 1].w);
            af[ks] = fr.v;
        }
    };
    cvtbuf(XA);   // frags for t0=0

    auto do_macro = [&](float4 (&Xre)[8], float4 (&Xcv)[8], int t0) {
        // ===== gx for 2 packed steps (x single-bf16) =====
        f32x4 axr[2], axz[2], axn[2];
        #pragma unroll
        for (int n2 = 0; n2 < 2; ++n2) {
            axr[n2] = (f32x4){bxr[n2], bxr[n2], bxr[n2], bxr[n2]};
            axz[n2] = (f32x4){bxz[n2], bxz[n2], bxz[n2], bxz[n2]};
            axn[n2] = (f32x4){bxn[n2], bxn[n2], bxn[n2], bxn[n2]};
            const int tr = (0 + wv * 2 + n2) * 2048;   // short-index tile bases
            const int tz = (4 + wv * 2 + n2) * 2048;
            const int tn = (8 + wv * 2 + n2) * 2048;
            #pragma unroll
            for (int ks = 0; ks < 4; ++ks) {
                axr[n2] = __builtin_amdgcn_mfma_f32_16x16x32_bf16(
                    af[ks], *(const short8*)&wihf[tr + ks * 512 + j * 8], axr[n2], 0, 0, 0);
                axz[n2] = __builtin_amdgcn_mfma_f32_16x16x32_bf16(
                    af[ks], *(const short8*)&wihf[tz + ks * 512 + j * 8], axz[n2], 0, 0, 0);
                axn[n2] = __builtin_amdgcn_mfma_f32_16x16x32_bf16(
                    af[ks], *(const short8*)&wihf[tn + ks * 512 + j * 8], axn[n2], 0, 0, 0);
            }
        }
        // ===== prefetch x for t0+4 =====
        {
            int tl = t0 + 4; if (tl > 254) tl = 254;
            const float* lp = xlane + (size_t)tl * F_;
            #pragma unroll
            for (int ks = 0; ks < 4; ++ks) {
                Xre[2 * ks]     = *(const float4*)(lp + ks * 32);
                Xre[2 * ks + 1] = *(const float4*)(lp + ks * 32 + 4);
            }
        }
        // ===== two recurrence steps =====
        auto step = [&](int s) {
            f32x4 agr[2], agz[2], agn[2];
            #pragma unroll
            for (int n2 = 0; n2 < 2; ++n2) {
                agr[n2] = (f32x4){bgr[n2], bgr[n2], bgr[n2], bgr[n2]};
                agz[n2] = (f32x4){bgz[n2], bgz[n2], bgz[n2], bgz[n2]};
                agn[n2] = (f32x4){bgn[n2], bgn[n2], bgn[n2], bgn[n2]};
                const int tr = (0 + wv * 2 + n2) * 1024;
                const int tz = (4 + wv * 2 + n2) * 1024;
                const int tn = (8 + wv * 2 + n2) * 1024;
                #pragma unroll
                for (int ks2 = 0; ks2 < 2; ++ks2) {
                    const short8 br = *(const short8*)&whhf[tr + ks2 * 512 + j * 8];
                    const short8 bz = *(const short8*)&whhf[tz + ks2 * 512 + j * 8];
                    const short8 bn = *(const short8*)&whhf[tn + ks2 * 512 + j * 8];
                    agr[n2] = __builtin_amdgcn_mfma_f32_16x16x32_bf16(hh[ks2], br, agr[n2], 0, 0, 0);
                    agr[n2] = __builtin_amdgcn_mfma_f32_16x16x32_bf16(hl[ks2], br, agr[n2], 0, 0, 0);
                    agz[n2] = __builtin_amdgcn_mfma_f32_16x16x32_bf16(hh[ks2], bz, agz[n2], 0, 0, 0);
                    agz[n2] = __builtin_amdgcn_mfma_f32_16x16x32_bf16(hl[ks2], bz, agz[n2], 0, 0, 0);
                    agn[n2] = __builtin_amdgcn_mfma_f32_16x16x32_bf16(hh[ks2], bn, agn[n2], 0, 0, 0);
                    agn[n2] = __builtin_amdgcn_mfma_f32_16x16x32_bf16(hl[ks2], bn, agn[n2], 0, 0, 0);
                }
            }
            // gates: active lanes q>>1 == s hold this step's gx rows (C rows 8s..8s+7)
            if ((q >> 1) == s) {
                const int rowsel = q & 1;     // dedupe the m&4 replication
                #pragma unroll
                for (int n2 = 0; n2 < 2; ++n2) {
                    const int d = d0 + n2 * 16;
                    #pragma unroll
                    for (int rl = 0; rl < 2; ++rl) {
                        const int row = rowsel * 2 + rl;
                        const float vr  = rowsel ? axr[n2][2 + rl] + agr[n2][2 + rl]
                                                 : axr[n2][rl]     + agr[n2][rl];
                        const float vz  = rowsel ? axz[n2][2 + rl] + agz[n2][2 + rl]
                                                 : axz[n2][rl]     + agz[n2][rl];
                        const float vnx = rowsel ? axn[n2][2 + rl] : axn[n2][rl];
                        const float vnh = rowsel ? agn[n2][2 + rl] : agn[n2][rl];
                        const float r = sigmoid_f(vr);
                        const float z = sigmoid_f(vz);
                        const float n = tanh_f(vnx + r * vnh);
                        const float hp =
                            __uint_as_float(((unsigned int)(unsigned short)hhi_l[s][row][d]) << 16) +
                            __uint_as_float(((unsigned int)(unsigned short)hlo_l[s][row][d]) << 16);
                        const float hn = n + z * (hp - n);
                        const unsigned int uh = __float_as_uint(hn);
                        const unsigned int rr = uh + 0x7fffu + ((uh >> 16) & 1u);
                        const float hif = __uint_as_float(rr & 0xffff0000u);
                        const float lof = hn - hif;
                        const unsigned int ul = __float_as_uint(lof);
                        const unsigned int r2 = ul + 0x7fffu + ((ul >> 16) & 1u);
                        hhi_l[s ^ 1][row][d] = (short)(rr >> 16);
                        hlo_l[s ^ 1][row][d] = (short)(r2 >> 16);
                    }
                }
            }
            __syncthreads();
            // reload h A-frags for next step (zero-convert: pre-split bf16 in LDS)
            #pragma unroll
            for (int ks2 = 0; ks2 < 2; ++ks2) {
                hh[ks2] = *(const short8*)&hhi_l[s ^ 1][xrow][ks2 * 32 + q * 8];
                hl[ks2] = *(const short8*)&hlo_l[s ^ 1][xrow][ks2 * 32 + q * 8];
            }
        };
        step(0);
        step(1);
        // ===== convert next macro's x =====
        cvtbuf(Xcv);
    };

    #pragma unroll 1
    for (int t0 = 0; t0 < T_; t0 += 4) {
        do_macro(XA, XB, t0);
        do_macro(XB, XA, t0 + 2);
    }

    // ===== epilogue: out[brow+r] = h[r] . fc_w + fc_b  (final h in buffer 0) =====
    {
        const int row = q;
        const float hv0 =
            __uint_as_float(((unsigned int)(unsigned short)hhi_l[0][row][d0]) << 16) +
            __uint_as_float(((unsigned int)(unsigned short)hlo_l[0][row][d0]) << 16);
        const float hv1 =
            __uint_as_float(((unsigned int)(unsigned short)hhi_l[0][row][d0 + 16]) << 16) +
            __uint_as_float(((unsigned int)(unsigned short)hlo_l[0][row][d0 + 16]) << 16);
        float partial = hv0 * fw0 + hv1 * fw1;
        #pragma unroll
        for (int m = 1; m <= 8; m <<= 1) partial += __shfl_xor(partial, m, 64);
        if (c == 0) wred[wv][q] = partial;
        __syncthreads();
        if (tid < 4) out[brow + tid] = wred[0][tid] + wred[1][tid] + fc_b[0];
    }
}

extern "C" void kernel_launch(void* const* d_in, const int* in_sizes, int n_in,
                              void* d_out, int out_size, void* d_ws, size_t ws_size,
                              hipStream_t stream)
{
    (void)in_sizes; (void)n_in; (void)out_size; (void)d_ws; (void)ws_size;
    const float* x    = (const float*)d_in[0];
    const float* w_ih = (const float*)d_in[1];
    const float* w_hh = (const float*)d_in[2];
    const float* b_ih = (const float*)d_in[3];
    const float* b_hh = (const float*)d_in[4];
    const float* fc_w = (const float*)d_in[5];
    const float* fc_b = (const float*)d_in[6];
    float* out = (float*)d_out;

    gru_fused<<<dim3(B_ / 4), 128, 0, stream>>>(
        x, w_ih, w_hh, b_ih, b_hh, fc_w, fc_b, out);
}